// Round 13
// baseline (216.371 us; speedup 1.0000x reference)
//
#include <hip/hip_runtime.h>

#define N_TOK 3072
#define DM    256
#define NH    8
#define DK    32
#define QT32  (N_TOK / 32)    // 96 q-tiles of 32 rows
#define KSPAN (N_TOK / 4)     // 768 keys per wave
#define NIT   (KSPAN / 64)    // 12 iterations of 64 keys
#define PROJ_B 576            // 48 m-tiles x 4 n-tiles x 3 inputs

typedef __attribute__((ext_vector_type(8))) short  short8;
typedef __attribute__((ext_vector_type(4))) float  f32x4;

// fp32 -> bf16 bits, round-to-nearest-even
__device__ __forceinline__ unsigned short f2bf(float f) {
    union { float f; unsigned int u; } v; v.f = f;
    unsigned int r = (v.u + 0x7fffu + ((v.u >> 16) & 1u)) >> 16;
    return (unsigned short)r;
}
// fp32 -> bf16 bits, round-half-up (2 VALU; same 0.5-ulp bound; attn hot path)
__device__ __forceinline__ unsigned short f2bf_fast(float f) {
    union { float f; unsigned int u; } v; v.f = f;
    return (unsigned short)((v.u + 0x8000u) >> 16);
}
// two float4 -> bf16x8 fragment
__device__ __forceinline__ short8 cast8(const float* p) {
    const float4 x0 = *reinterpret_cast<const float4*>(p);
    const float4 x1 = *reinterpret_cast<const float4*>(p + 4);
    short8 t;
    t[0] = (short)f2bf(x0.x); t[1] = (short)f2bf(x0.y);
    t[2] = (short)f2bf(x0.z); t[3] = (short)f2bf(x0.w);
    t[4] = (short)f2bf(x1.x); t[5] = (short)f2bf(x1.y);
    t[6] = (short)f2bf(x1.z); t[7] = (short)f2bf(x1.w);
    return t;
}

// ---------------- Kernel 1: prep ∥ proj (independent block ranges, one launch)
// blocks [0,3072):      adjs[r][k] = bf16( adj[r][k] * lam1 / (rowsum + eps) )
// blocks [3072,3648):   Q/K/V projection GEMMs, fp32 operands cast in-register
//   (no castbuf: removes the prep->proj dependency so both halves co-schedule)
//   z=0: Qh[h][n][32] scaled by log2(e)/sqrt(DK); z=1: Kh; z=2: Vt[256][3072]
__global__ __launch_bounds__(256, 2) void prep_proj_kernel(
    const float* __restrict__ adj, const float* __restrict__ lambdas,
    const float* __restrict__ query, const float* __restrict__ key,
    const float* __restrict__ value,
    const float* __restrict__ Wq, const float* __restrict__ Wk,
    const float* __restrict__ Wv,
    const float* __restrict__ bq, const float* __restrict__ bk,
    const float* __restrict__ bv,
    unsigned short* __restrict__ adjs,
    unsigned short* __restrict__ Qh, unsigned short* __restrict__ Kh,
    unsigned short* __restrict__ Vt)
{
    __shared__ __align__(16) unsigned short Ts[64][72];  // proj z==2 transpose
    __shared__ float ps[4];                              // adj rowsum partials

    const int b = blockIdx.x, t = threadIdx.x;
    if (b < N_TOK) {
        // ---- adjacency normalize
        const int r = b;
        const float4* src = reinterpret_cast<const float4*>(adj + (size_t)r * N_TOK);
        float4 v[3];
        float s = 0.f;
        #pragma unroll
        for (int i = 0; i < 3; ++i) {
            v[i] = src[t + i * 256];
            s += v[i].x + v[i].y + v[i].z + v[i].w;
        }
        #pragma unroll
        for (int off = 1; off < 64; off <<= 1) s += __shfl_xor(s, off, 64);
        if ((t & 63) == 0) ps[t >> 6] = s;
        __syncthreads();
        const float tot = ps[0] + ps[1] + ps[2] + ps[3];
        const float sc = lambdas[1] / (tot + 1e-6f);
        ushort4* dp = reinterpret_cast<ushort4*>(adjs + (size_t)r * N_TOK);
        #pragma unroll
        for (int i = 0; i < 3; ++i) {
            ushort4 o;
            o.x = f2bf(v[i].x * sc); o.y = f2bf(v[i].y * sc);
            o.z = f2bf(v[i].z * sc); o.w = f2bf(v[i].w * sc);
            dp[t + i * 256] = o;
        }
        return;
    }

    // ---- projection GEMM: idx -> (z, m-tile, n-tile)
    const int idx = b - N_TOK;
    const int z = idx / 192, rem = idx % 192;
    const float* A = (z == 0) ? query : (z == 1) ? key : value;
    const float* W = (z == 0) ? Wq : (z == 1) ? Wk : Wv;
    const float* bias = (z == 0) ? bq : (z == 1) ? bk : bv;

    const int lane = t & 63, wave = t >> 6;
    const int quad = lane >> 4, l15 = lane & 15;
    const int wm = wave >> 1, wn = wave & 1;
    const int m0 = (rem >> 2) * 64, n0 = (rem & 3) * 64;
    const int mw = m0 + wm * 32, nw = n0 + wn * 32;

    f32x4 acc[2][2] = {};

    #pragma unroll
    for (int ks = 0; ks < DM / 32; ++ks) {
        short8 afr[2], bfr[2];
        #pragma unroll
        for (int i = 0; i < 2; ++i)
            afr[i] = cast8(A + (size_t)(mw + i * 16 + l15) * DM + ks * 32 + quad * 8);
        #pragma unroll
        for (int j = 0; j < 2; ++j)
            bfr[j] = cast8(W + (size_t)(nw + j * 16 + l15) * DM + ks * 32 + quad * 8);
        #pragma unroll
        for (int i = 0; i < 2; ++i)
            #pragma unroll
            for (int j = 0; j < 2; ++j)
                acc[i][j] = __builtin_amdgcn_mfma_f32_16x16x32_bf16(
                    afr[i], bfr[j], acc[i][j], 0, 0, 0);
    }

    float bias_j[2];
    bias_j[0] = bias[nw + l15];
    bias_j[1] = bias[nw + 16 + l15];

    if (z < 2) {
        // log2(e)/sqrt(32) folded into Q so attention uses native exp2
        const float scale = (z == 0) ? (0.17677669529663687f * 1.4426950408889634f) : 1.0f;
        unsigned short* out = (z == 0) ? Qh : Kh;
        #pragma unroll
        for (int i = 0; i < 2; ++i)
            #pragma unroll
            for (int j = 0; j < 2; ++j)
                #pragma unroll
                for (int r = 0; r < 4; ++r) {
                    const int m = mw + i * 16 + quad * 4 + r;
                    const int n = nw + j * 16 + l15;
                    const int hh = n >> 5, d = n & 31;
                    out[((size_t)hh * N_TOK + m) * DK + d] =
                        f2bf((acc[i][j][r] + bias_j[j]) * scale);
                }
    } else {
        #pragma unroll
        for (int i = 0; i < 2; ++i)
            #pragma unroll
            for (int j = 0; j < 2; ++j)
                #pragma unroll
                for (int r = 0; r < 4; ++r) {
                    const int ml = wm * 32 + i * 16 + quad * 4 + r;
                    const int nl = wn * 32 + j * 16 + l15;
                    Ts[nl][ml] = f2bf(acc[i][j][r] + bias_j[j]);
                }
        __syncthreads();
        const int nn = t >> 2, cc = (t & 3) * 16;
        const uint4 v0 = *reinterpret_cast<const uint4*>(&Ts[nn][cc]);
        const uint4 v1 = *reinterpret_cast<const uint4*>(&Ts[nn][cc + 8]);
        unsigned short* dp = Vt + (size_t)(n0 + nn) * N_TOK + m0 + cc;
        *reinterpret_cast<uint4*>(dp)     = v0;
        *reinterpret_cast<uint4*>(dp + 8) = v1;
    }
}

// ---------------- Kernel 2: fused attention + adjacency blend, 32 q-rows/block
// (byte-identical structure to R12's measured 51.8 µs kernel)
__global__ __launch_bounds__(256, 3) void attn_kernel(
    const unsigned short* __restrict__ Qh, const unsigned short* __restrict__ Kh,
    const unsigned short* __restrict__ Vt, const unsigned short* __restrict__ adjs,
    const float* __restrict__ lambdas,
    unsigned short* __restrict__ Xbf)
{
    const int bx = blockIdx.x;
    const int qt = bx % QT32, h = bx / QT32;
    const int tid  = threadIdx.x;
    const int lane = tid & 63, wave = tid >> 6;
    const int quad = lane >> 4, l15 = lane & 15;
    const int q0 = qt * 32;
    const int kbase = wave * KSPAN;

    __shared__ __align__(16) unsigned short Ps[4][2][16][72];
    float* smf = reinterpret_cast<float*>(Ps);
    float (*eO)[33] = reinterpret_cast<float (*)[33]>(smf);
    float (*eA)[33] = reinterpret_cast<float (*)[33]>(smf + 32 * 33);
    float* eL = smf + 2 * 32 * 33;

    const short8 qfrA = *reinterpret_cast<const short8*>(
        Qh + ((size_t)h * N_TOK + q0 + l15) * DK + quad * 8);
    const short8 qfrB = *reinterpret_cast<const short8*>(
        Qh + ((size_t)h * N_TOK + q0 + 16 + l15) * DK + quad * 8);

    const unsigned short* Kb  = Kh + ((size_t)h * N_TOK + l15) * DK + quad * 8;
    const unsigned short* Vb0 = Vt + (size_t)(h * DK + l15) * N_TOK + quad * 8;
    const unsigned short* Vb1 = Vt + (size_t)(h * DK + 16 + l15) * N_TOK + quad * 8;
    const unsigned short* AbA = adjs + (size_t)(q0 + l15) * N_TOK + quad * 8;
    const unsigned short* AbB = adjs + (size_t)(q0 + 16 + l15) * N_TOK + quad * 8;

    f32x4 oA0 = {}, oA1 = {}, aA0 = {}, aA1 = {};
    f32x4 oB0 = {}, oB1 = {}, aB0 = {}, aB1 = {};
    float llA[4] = {0.f, 0.f, 0.f, 0.f}, llB[4] = {0.f, 0.f, 0.f, 0.f};

    for (int it = 0; it < NIT; ++it) {
        const int k0 = kbase + it * 64;

        short8 kf[4];
        #pragma unroll
        for (int kt = 0; kt < 4; ++kt)
            kf[kt] = *reinterpret_cast<const short8*>(Kb + (size_t)(k0 + kt * 16) * DK);
        short8 v0[2], v1[2], afA[2], afB[2];
        #pragma unroll
        for (int ss = 0; ss < 2; ++ss) {
            v0[ss]  = *reinterpret_cast<const short8*>(Vb0 + k0 + ss * 32);
            v1[ss]  = *reinterpret_cast<const short8*>(Vb1 + k0 + ss * 32);
            afA[ss] = *reinterpret_cast<const short8*>(AbA + k0 + ss * 32);
            afB[ss] = *reinterpret_cast<const short8*>(AbB + k0 + ss * 32);
        }

        #pragma unroll
        for (int kt = 0; kt < 4; ++kt) {
            f32x4 sa = {0.f, 0.f, 0.f, 0.f}, sb = {0.f, 0.f, 0.f, 0.f};
            sa = __builtin_amdgcn_mfma_f32_16x16x32_bf16(qfrA, kf[kt], sa, 0, 0, 0);
            sb = __builtin_amdgcn_mfma_f32_16x16x32_bf16(qfrB, kf[kt], sb, 0, 0, 0);
            #pragma unroll
            for (int r = 0; r < 4; ++r) {
                const float ea = __builtin_amdgcn_exp2f(sa[r]);
                const float eb = __builtin_amdgcn_exp2f(sb[r]);
                llA[r] += ea;
                llB[r] += eb;
                Ps[wave][0][quad * 4 + r][kt * 16 + l15] = f2bf_fast(ea);
                Ps[wave][1][quad * 4 + r][kt * 16 + l15] = f2bf_fast(eb);
            }
        }
        __builtin_amdgcn_wave_barrier();

        #pragma unroll
        for (int ss = 0; ss < 2; ++ss) {
            const short8 pfA = *reinterpret_cast<const short8*>(
                &Ps[wave][0][l15][ss * 32 + quad * 8]);
            const short8 pfB = *reinterpret_cast<const short8*>(
                &Ps[wave][1][l15][ss * 32 + quad * 8]);
            oA0 = __builtin_amdgcn_mfma_f32_16x16x32_bf16(pfA,     v0[ss], oA0, 0, 0, 0);
            oA1 = __builtin_amdgcn_mfma_f32_16x16x32_bf16(pfA,     v1[ss], oA1, 0, 0, 0);
            aA0 = __builtin_amdgcn_mfma_f32_16x16x32_bf16(afA[ss], v0[ss], aA0, 0, 0, 0);
            aA1 = __builtin_amdgcn_mfma_f32_16x16x32_bf16(afA[ss], v1[ss], aA1, 0, 0, 0);
            oB0 = __builtin_amdgcn_mfma_f32_16x16x32_bf16(pfB,     v0[ss], oB0, 0, 0, 0);
            oB1 = __builtin_amdgcn_mfma_f32_16x16x32_bf16(pfB,     v1[ss], oB1, 0, 0, 0);
            aB0 = __builtin_amdgcn_mfma_f32_16x16x32_bf16(afB[ss], v0[ss], aB0, 0, 0, 0);
            aB1 = __builtin_amdgcn_mfma_f32_16x16x32_bf16(afB[ss], v1[ss], aB1, 0, 0, 0);
        }
        __builtin_amdgcn_wave_barrier();
    }

    #pragma unroll
    for (int off = 1; off < 16; off <<= 1)
        #pragma unroll
        for (int r = 0; r < 4; ++r) {
            llA[r] += __shfl_xor(llA[r], off, 64);
            llB[r] += __shfl_xor(llB[r], off, 64);
        }

    __syncthreads();   // all waves done with Ps before aliasing as eO/eA/eL

    for (int w = 0; w < 4; ++w) {
        if (wave == w) {
            #pragma unroll
            for (int r = 0; r < 4; ++r) {
                const int rA = quad * 4 + r, rB = 16 + quad * 4 + r;
                if (w == 0) {
                    eO[rA][l15] = oA0[r];  eO[rA][16 + l15] = oA1[r];
                    eO[rB][l15] = oB0[r];  eO[rB][16 + l15] = oB1[r];
                    eA[rA][l15] = aA0[r];  eA[rA][16 + l15] = aA1[r];
                    eA[rB][l15] = aB0[r];  eA[rB][16 + l15] = aB1[r];
                    if (l15 == 0) { eL[rA] = llA[r]; eL[rB] = llB[r]; }
                } else {
                    eO[rA][l15] += oA0[r];  eO[rA][16 + l15] += oA1[r];
                    eO[rB][l15] += oB0[r];  eO[rB][16 + l15] += oB1[r];
                    eA[rA][l15] += aA0[r];  eA[rA][16 + l15] += aA1[r];
                    eA[rB][l15] += aB0[r];  eA[rB][16 + l15] += aB1[r];
                    if (l15 == 0) { eL[rA] += llA[r]; eL[rB] += llB[r]; }
                }
            }
        }
        __syncthreads();
    }

    {
        const int row = tid >> 3, d4 = (tid & 7) * 4;
        const float invL = lambdas[0] / eL[row];
        ushort4 o;
        o.x = f2bf(eO[row][d4 + 0] * invL + eA[row][d4 + 0]);
        o.y = f2bf(eO[row][d4 + 1] * invL + eA[row][d4 + 1]);
        o.z = f2bf(eO[row][d4 + 2] * invL + eA[row][d4 + 2]);
        o.w = f2bf(eO[row][d4 + 3] * invL + eA[row][d4 + 3]);
        *reinterpret_cast<ushort4*>(Xbf + (size_t)(q0 + row) * DM + h * DK + d4) = o;
    }
}

// ---------------- Kernel 3: out = Xbf @ Wo^T + bo (fp32 out, Wo cast in-loop)
__global__ __launch_bounds__(256) void outproj_kernel(
    const unsigned short* __restrict__ Xbf, const float* __restrict__ Wo,
    const float* __restrict__ bo, float* __restrict__ out)
{
    const int tid  = threadIdx.x;
    const int lane = tid & 63, wave = tid >> 6;
    const int quad = lane >> 4, l15 = lane & 15;
    const int m0 = blockIdx.x * 16, n0 = blockIdx.y * 64;
    const int nw = n0 + wave * 16;

    f32x4 acc = {};

    #pragma unroll
    for (int ks = 0; ks < DM / 32; ++ks) {
        const short8 afr = *reinterpret_cast<const short8*>(
            Xbf + (size_t)(m0 + l15) * DM + ks * 32 + quad * 8);
        const short8 bfr = cast8(Wo + (size_t)(nw + l15) * DM + ks * 32 + quad * 8);
        acc = __builtin_amdgcn_mfma_f32_16x16x32_bf16(afr, bfr, acc, 0, 0, 0);
    }
    const float bias = bo[nw + l15];
    #pragma unroll
    for (int r = 0; r < 4; ++r)
        out[(size_t)(m0 + quad * 4 + r) * DM + nw + l15] = acc[r] + bias;
}

extern "C" void kernel_launch(void* const* d_in, const int* in_sizes, int n_in,
                              void* d_out, int out_size, void* d_ws, size_t ws_size,
                              hipStream_t stream)
{
    const float* query   = (const float*)d_in[0];
    const float* key_    = (const float*)d_in[1];
    const float* value   = (const float*)d_in[2];
    const float* adj     = (const float*)d_in[4];
    const float* lambdas = (const float*)d_in[5];
    const float* Wq      = (const float*)d_in[6];
    const float* bq      = (const float*)d_in[7];
    const float* Wk      = (const float*)d_in[8];
    const float* bk      = (const float*)d_in[9];
    const float* Wv      = (const float*)d_in[10];
    const float* bv      = (const float*)d_in[11];
    const float* Wo      = (const float*)d_in[12];
    const float* bo      = (const float*)d_in[13];

    char* p = (char*)d_ws;
    unsigned short* Qh   = (unsigned short*)p;  p += (size_t)N_TOK * DM * 2;     // 1.5 MB
    unsigned short* Kh   = (unsigned short*)p;  p += (size_t)N_TOK * DM * 2;
    unsigned short* Vt   = (unsigned short*)p;  p += (size_t)DM * N_TOK * 2;
    unsigned short* adjs = (unsigned short*)p;  p += (size_t)N_TOK * N_TOK * 2;  // 18.9 MB
    unsigned short* Xbf  = (unsigned short*)p;  p += (size_t)N_TOK * DM * 2;

    prep_proj_kernel<<<N_TOK + PROJ_B, 256, 0, stream>>>(
        adj, lambdas, query, key_, value, Wq, Wk, Wv, bq, bk, bv,
        adjs, Qh, Kh, Vt);
    attn_kernel<<<QT32 * NH, 256, 0, stream>>>(Qh, Kh, Vt, adjs, lambdas, Xbf);
    outproj_kernel<<<dim3(N_TOK / 16, DM / 64), 256, 0, stream>>>(
        Xbf, Wo, bo, (float*)d_out);
}